// Round 4
// baseline (353.601 us; speedup 1.0000x reference)
//
#include <hip/hip_runtime.h>
#include <math.h>

// DiffDispatchLP: batched (256x) PDHG, 400 iters.
// R4: ONE WAVE PER ITEM, ZERO LDS, FULLY REGISTER-RESIDENT.
// Lesson from R1/R2/R3: T(waves) = 3150/1522/1325 cy at W=1/4/8 -- the kernel
// family is bound by ~110 LDS instructions/iter + 2 exposed post-barrier LDS
// latency bursts, NOT by VALU (VALUBusy <= 24%) and NOT by barrier arrivals.
// R4 removes the LDS round-trips entirely: lane l holds t=2l (even chunk) and
// t=2l+1 (odd chunk), l<48. All K/K^T couplings are t-offsets of +-1..3 =>
// half are same-lane (free), rest are __shfl by 1-2 (~28/iter on the permute
// network). Total-charge row via verified DPP wave_sum64. No barriers at all.
// Row-existence masks folded into per-row sigma multipliers (dual starts 0,
// sigma_masked=0 => stays 0 forever; shuffle edges then read natural zeros).
//
// LP recap (T=96): vars c,d,yc,yd,s per t. Rows:
//  box(13/t): c<=195,d<=195,-c,-d,-yc,yc<=1,-yd,yd<=1,-s,s<=800,yc+yd<=1,
//             c-195yc<=0, d-195yd<=0
//  ramp(4/t, t>=1): +-(c[t]-c[t-1])<=65, +-(d[t]-d[t-1])<=65
//  switch(2/t, t<=94): yc[t]+yd[t+1]<=1, yd[t]+yc[t+1]<=1
//  min-dur(v in {yc,yd}, k=1..3, t<=95-k): v[t]-v[t-1]-v[t+k]<=0
//  total-charge: 0.25*sum(c)<=1200
//  eq(t=0..95): s[t]-s[t-1]-eta*dt*c[t]+dt/eta*d[t]=0 ; eq96: s[95]=0

#define NITER 400
#define PITER 10

// Full wave64 sum via DPP (VALU pipe) -- verified in R1 (row_shr:N => dst[i]=src[i-N]).
__device__ __forceinline__ float wave_sum64(float v) {
  float r = v;
  int x;
  x = __builtin_amdgcn_update_dpp(0, __float_as_int(r), 0x111, 0xf, 0xf, true);
  r += __int_as_float(x);
  x = __builtin_amdgcn_update_dpp(0, __float_as_int(r), 0x112, 0xf, 0xf, true);
  r += __int_as_float(x);
  x = __builtin_amdgcn_update_dpp(0, __float_as_int(r), 0x114, 0xf, 0xf, true);
  r += __int_as_float(x);
  x = __builtin_amdgcn_update_dpp(0, __float_as_int(r), 0x118, 0xf, 0xf, true);
  r += __int_as_float(x);
  x = __builtin_amdgcn_update_dpp(0, __float_as_int(r), 0x142, 0xa, 0xf, true);
  r += __int_as_float(x);
  x = __builtin_amdgcn_update_dpp(0, __float_as_int(r), 0x143, 0xc, 0xf, true);
  r += __int_as_float(x);
  return __int_as_float(__builtin_amdgcn_readlane(__float_as_int(r), 63));
}

__global__ __launch_bounds__(64, 1)
void lp_solve_kernel(const float* __restrict__ price, float* __restrict__ out) {
  const int lane = threadIdx.x;
  const int bi = blockIdx.x;
  const double ETA_D = sqrt(0.91);
  const float cET = (float)(-(ETA_D * 0.25));  // -ETA*DT (eq coeff on c)
  const float cDE = (float)(0.25 / ETA_D);     // DT/ETA (eq coeff on d)

  // lane l: even chunk p=0 -> t=2l, odd chunk p=1 -> t=2l+1; valid l<48.
  const float act = (lane < 48) ? 1.f : 0.f;
  // 0/1 row-existence masks (power mode); PDHG uses sigma*mask versions.
  const float m_r[2]  = { (lane >= 1 && lane < 48) ? 1.f : 0.f, act };  // ramp t>=1
  const float m_sw[2] = { act, (lane <= 46) ? 1.f : 0.f };              // sw t<=94
  const float m_md[3][2] = {
    { act,                        (lane <= 46) ? 1.f : 0.f },           // k=1: t<=94
    { (lane <= 46) ? 1.f : 0.f,   (lane <= 46) ? 1.f : 0.f },           // k=2: t<=93
    { (lane <= 46) ? 1.f : 0.f,   (lane <= 45) ? 1.f : 0.f }            // k=3: t<=92
  };

  // shift helpers: shup*z zero-fill at the low edge (t<0); shdn* rely on
  // source lanes >=48 being exactly 0 (all duals & xbar are masked-zero there).
  auto shup1z = [&](float x) { float y = __shfl_up(x, 1, 64); return (lane >= 1) ? y : 0.f; };
  auto shup2z = [&](float x) { float y = __shfl_up(x, 2, 64); return (lane >= 2) ? y : 0.f; };
  auto shdn1  = [&](float x) { return __shfl_down(x, 1, 64); };
  auto shdn2  = [&](float x) { return __shfl_down(x, 2, 64); };

  // ---------------- state (all registers) ----------------
  float xc[2] = {0, 0}, xd[2] = {0, 0}, xyc[2] = {0, 0}, xyd[2] = {0, 0}, xs[2] = {0, 0};
  float xbc[2] = {0, 0}, xbd[2] = {0, 0}, xbyc[2] = {0, 0}, xbyd[2] = {0, 0}, xbs[2] = {0, 0};
  float qc[2] = {0, 0}, qd[2] = {0, 0};
  float yb[2][13];
#pragma unroll
  for (int p = 0; p < 2; ++p)
#pragma unroll
    for (int i = 0; i < 13; ++i) yb[p][i] = 0.f;
  float ymc[2][3] = {{0, 0, 0}, {0, 0, 0}}, ymd[2][3] = {{0, 0, 0}, {0, 0, 0}};
  float yr[2][4] = {{0, 0, 0, 0}, {0, 0, 0, 0}};
  float sw0[2] = {0, 0}, sw1[2] = {0, 0};
  float yeq[2] = {0, 0};
  float yeq96 = 0.f, ytc = 0.f;
  float uc[2] = {0, 0}, ud[2] = {0, 0}, msc[2] = {0, 0}, msd[2] = {0, 0};

  float sigv = 0.f, tauv = 0.f;
  float sa = 0.f, sr[2] = {0, 0}, ssw[2] = {0, 0};
  float smd[3][2] = {{0, 0}, {0, 0}, {0, 0}};

  // ---------------- phase B: row dots / dual updates ----------------
  auto phaseB = [&](bool power) {
    // xbar neighbor shuffles
    float pxc[2], pxd[2], pxs[2], pxyc[2], pxyd[2];
    pxc[0]  = shup1z(xbc[1]);  pxc[1]  = xbc[0];
    pxd[0]  = shup1z(xbd[1]);  pxd[1]  = xbd[0];
    pxs[0]  = shup1z(xbs[1]);  pxs[1]  = xbs[0];
    pxyc[0] = shup1z(xbyc[1]); pxyc[1] = xbyc[0];
    pxyd[0] = shup1z(xbyd[1]); pxyd[1] = xbyd[0];
    float nyc1[2], nyc2[2], nyc3[2], nyd1[2], nyd2[2], nyd3[2];
    nyc1[1] = shdn1(xbyc[0]); nyc1[0] = xbyc[1];
    nyc2[1] = shdn1(xbyc[1]); nyc2[0] = nyc1[1];
    nyc3[1] = shdn2(xbyc[0]); nyc3[0] = nyc2[1];
    nyd1[1] = shdn1(xbyd[0]); nyd1[0] = xbyd[1];
    nyd2[1] = shdn1(xbyd[1]); nyd2[0] = nyd1[1];
    nyd3[1] = shdn2(xbyd[0]); nyd3[0] = nyd2[1];

#pragma unroll
    for (int p = 0; p < 2; ++p) {
      const float c_ = xbc[p], d_ = xbd[p], yc_ = xbyc[p], yd_ = xbyd[p], s_ = xbs[p];
      // BOX (13 rows; in power mode xbar is act-masked so raw dots are 0 on l>=48)
      if (power) {
        yb[p][0] = c_;   yb[p][1] = d_;
        yb[p][2] = -c_;  yb[p][3] = -d_;
        yb[p][4] = -yc_; yb[p][5] = yc_;
        yb[p][6] = -yd_; yb[p][7] = yd_;
        yb[p][8] = -s_;  yb[p][9] = s_;
        yb[p][10] = yc_ + yd_;
        yb[p][11] = c_ - 195.f * yc_;
        yb[p][12] = d_ - 195.f * yd_;
      } else {
        yb[p][0]  = fmaxf(yb[p][0]  + sa * (c_ - 195.f), 0.f);
        yb[p][1]  = fmaxf(yb[p][1]  + sa * (d_ - 195.f), 0.f);
        yb[p][2]  = fmaxf(yb[p][2]  - sa * c_,           0.f);
        yb[p][3]  = fmaxf(yb[p][3]  - sa * d_,           0.f);
        yb[p][4]  = fmaxf(yb[p][4]  - sa * yc_,          0.f);
        yb[p][5]  = fmaxf(yb[p][5]  + sa * (yc_ - 1.f),  0.f);
        yb[p][6]  = fmaxf(yb[p][6]  - sa * yd_,          0.f);
        yb[p][7]  = fmaxf(yb[p][7]  + sa * (yd_ - 1.f),  0.f);
        yb[p][8]  = fmaxf(yb[p][8]  - sa * s_,           0.f);
        yb[p][9]  = fmaxf(yb[p][9]  + sa * (s_ - 800.f), 0.f);
        yb[p][10] = fmaxf(yb[p][10] + sa * (yc_ + yd_ - 1.f), 0.f);
        yb[p][11] = fmaxf(yb[p][11] + sa * (c_ - 195.f * yc_), 0.f);
        yb[p][12] = fmaxf(yb[p][12] + sa * (d_ - 195.f * yd_), 0.f);
      }
      // MIN-DURATION: dot(k,t) = v[t] - v[t-1] - v[t+k]
      {
        float dc1 = yc_ - pxyc[p] - nyc1[p];
        float dc2 = yc_ - pxyc[p] - nyc2[p];
        float dc3 = yc_ - pxyc[p] - nyc3[p];
        float dd1 = yd_ - pxyd[p] - nyd1[p];
        float dd2 = yd_ - pxyd[p] - nyd2[p];
        float dd3 = yd_ - pxyd[p] - nyd3[p];
        if (power) {
          ymc[p][0] = m_md[0][p] * dc1; ymc[p][1] = m_md[1][p] * dc2; ymc[p][2] = m_md[2][p] * dc3;
          ymd[p][0] = m_md[0][p] * dd1; ymd[p][1] = m_md[1][p] * dd2; ymd[p][2] = m_md[2][p] * dd3;
        } else {
          ymc[p][0] = fmaxf(ymc[p][0] + smd[0][p] * dc1, 0.f);
          ymc[p][1] = fmaxf(ymc[p][1] + smd[1][p] * dc2, 0.f);
          ymc[p][2] = fmaxf(ymc[p][2] + smd[2][p] * dc3, 0.f);
          ymd[p][0] = fmaxf(ymd[p][0] + smd[0][p] * dd1, 0.f);
          ymd[p][1] = fmaxf(ymd[p][1] + smd[1][p] * dd2, 0.f);
          ymd[p][2] = fmaxf(ymd[p][2] + smd[2][p] * dd3, 0.f);
        }
      }
      // RAMP
      {
        float dc = c_ - pxc[p], dd = d_ - pxd[p];
        if (power) {
          yr[p][0] = m_r[p] * dc; yr[p][1] = -m_r[p] * dc;
          yr[p][2] = m_r[p] * dd; yr[p][3] = -m_r[p] * dd;
        } else {
          yr[p][0] = fmaxf(yr[p][0] + sr[p] * (dc - 65.f),  0.f);
          yr[p][1] = fmaxf(yr[p][1] + sr[p] * (-dc - 65.f), 0.f);
          yr[p][2] = fmaxf(yr[p][2] + sr[p] * (dd - 65.f),  0.f);
          yr[p][3] = fmaxf(yr[p][3] + sr[p] * (-dd - 65.f), 0.f);
        }
      }
      // SWITCH
      {
        float d0 = yc_ + nyd1[p], d1 = yd_ + nyc1[p];
        if (power) { sw0[p] = m_sw[p] * d0; sw1[p] = m_sw[p] * d1; }
        else {
          sw0[p] = fmaxf(sw0[p] + ssw[p] * (d0 - 1.f), 0.f);
          sw1[p] = fmaxf(sw1[p] + ssw[p] * (d1 - 1.f), 0.f);
        }
      }
      // EQUALITY (free dual)
      {
        float de = s_ - pxs[p] + cET * c_ + cDE * d_;
        if (power) yeq[p] = act * de;
        else yeq[p] += sa * de;
      }
      // combos consumed by next gather (masked-zero rows keep these exact)
      uc[p] = yr[p][0] - yr[p][1];
      ud[p] = yr[p][2] - yr[p][3];
      msc[p] = ymc[p][0] + ymc[p][1] + ymc[p][2];
      msd[p] = ymd[p][0] + ymd[p][1] + ymd[p][2];
    }
    // eq96 (s[95]=0) and total-charge, both wave-uniform
    {
      float s95 = __shfl(xbs[1], 47, 64);
      if (power) yeq96 = s95; else yeq96 += sigv * s95;
      float tot = wave_sum64(xbc[0] + xbc[1]);
      if (power) ytc = 0.25f * tot;
      else ytc = fmaxf(ytc + sigv * (0.25f * tot - 1200.f), 0.f);
    }
  };

  // ---------------- phase A: K^T y gather, all 10 column-chunks ----------------
  float gc[2], gd[2], gyc[2], gyd[2], gs[2];
  auto gather = [&]() {
    float ucn[2], udn[2], mscn[2], msdn[2], eqn[2];
    ucn[0] = uc[1];   ucn[1] = shdn1(uc[0]);
    udn[0] = ud[1];   udn[1] = shdn1(ud[0]);
    mscn[0] = msc[1]; mscn[1] = shdn1(msc[0]);
    msdn[0] = msd[1]; msdn[1] = shdn1(msd[0]);
    eqn[0] = yeq[1];
    { float tdn = shdn1(yeq[0]); eqn[1] = (lane == 47) ? -yeq96 : tdn; }
    float sw1p[2], sw0p[2];
    sw1p[0] = shup1z(sw1[1]); sw1p[1] = sw1[0];
    sw0p[0] = shup1z(sw0[1]); sw0p[1] = sw0[0];
    float pc1[2], pc2[2], pc3[2], pd1[2], pd2[2], pd3[2];
    pc1[0] = shup1z(ymc[1][0]); pc1[1] = ymc[0][0];
    pc2[0] = shup1z(ymc[0][1]); pc2[1] = shup1z(ymc[1][1]);
    pc3[0] = shup2z(ymc[1][2]); pc3[1] = shup1z(ymc[0][2]);
    pd1[0] = shup1z(ymd[1][0]); pd1[1] = ymd[0][0];
    pd2[0] = shup1z(ymd[0][1]); pd2[1] = shup1z(ymd[1][1]);
    pd3[0] = shup2z(ymd[1][2]); pd3[1] = shup1z(ymd[0][2]);
#pragma unroll
    for (int p = 0; p < 2; ++p) {
      gc[p] = (yb[p][0] - yb[p][2] + yb[p][11]) + uc[p] - ucn[p]
            + 0.25f * ytc + cET * yeq[p];
      gd[p] = (yb[p][1] - yb[p][3] + yb[p][12]) + ud[p] - udn[p] + cDE * yeq[p];
      gyc[p] = (-yb[p][4] + yb[p][5] + yb[p][10] - 195.f * yb[p][11])
             + sw0[p] + sw1p[p] + msc[p] - mscn[p] - pc1[p] - pc2[p] - pc3[p];
      gyd[p] = (-yb[p][6] + yb[p][7] + yb[p][10] - 195.f * yb[p][12])
             + sw1[p] + sw0p[p] + msd[p] - msdn[p] - pd1[p] - pd2[p] - pd3[p];
      gs[p] = (-yb[p][8] + yb[p][9]) + yeq[p] - eqn[p];
    }
  };

  // ================= power iteration: ||K||_2 =================
#pragma unroll
  for (int p = 0; p < 2; ++p) {
    xbc[p] = act; xbd[p] = act; xbyc[p] = act; xbyd[p] = act; xbs[p] = act;
  }
  float lam2 = 1.f;
  for (int pit = 0; pit < PITER; ++pit) {
    phaseB(true);
    gather();
    float part = gc[0] * gc[0] + gc[1] * gc[1] + gd[0] * gd[0] + gd[1] * gd[1]
               + gyc[0] * gyc[0] + gyc[1] * gyc[1] + gyd[0] * gyd[0] + gyd[1] * gyd[1]
               + gs[0] * gs[0] + gs[1] * gs[1];
    part *= act;
    lam2 = sqrtf(wave_sum64(part));
    float inv = act / lam2;
#pragma unroll
    for (int p = 0; p < 2; ++p) {
      xbc[p] = gc[p] * inv; xbd[p] = gd[p] * inv;
      xbyc[p] = gyc[p] * inv; xbyd[p] = gyd[p] * inv; xbs[p] = gs[p] * inv;
    }
  }
  tauv = (float)(0.9 / sqrt((double)lam2));
  sigv = tauv;
  // sigma*mask row multipliers (loop-invariant)
  sa = sigv * act;
  sr[0] = sigv * m_r[0];  sr[1] = sigv * m_r[1];
  ssw[0] = sigv * m_sw[0]; ssw[1] = sigv * m_sw[1];
#pragma unroll
  for (int k = 0; k < 3; ++k) { smd[k][0] = sigv * m_md[k][0]; smd[k][1] = sigv * m_md[k][1]; }

  // reset all state for PDHG
#pragma unroll
  for (int p = 0; p < 2; ++p) {
#pragma unroll
    for (int i = 0; i < 13; ++i) yb[p][i] = 0.f;
#pragma unroll
    for (int k = 0; k < 3; ++k) { ymc[p][k] = 0.f; ymd[p][k] = 0.f; }
#pragma unroll
    for (int k = 0; k < 4; ++k) yr[p][k] = 0.f;
    sw0[p] = 0.f; sw1[p] = 0.f; yeq[p] = 0.f;
    uc[p] = 0.f; ud[p] = 0.f; msc[p] = 0.f; msd[p] = 0.f;
    xbc[p] = 0.f; xbd[p] = 0.f; xbyc[p] = 0.f; xbyd[p] = 0.f; xbs[p] = 0.f;
    xc[p] = 0.f; xd[p] = 0.f; xyc[p] = 0.f; xyd[p] = 0.f; xs[p] = 0.f;
  }
  yeq96 = 0.f; ytc = 0.f;

  // q loads (lanes >=48 nullified by tau*act)
  {
    const int l2 = (lane < 48) ? lane : 0;
    float p0 = price[bi * 96 + 2 * l2];
    float p1 = price[bi * 96 + 2 * l2 + 1];
    qc[0] = 0.25f * p0;  qc[1] = 0.25f * p1;
    qd[0] = -0.25f * p0; qd[1] = -0.25f * p1;
  }

  // ================= PDHG =================
  const float ta = tauv * act;
#pragma unroll 1
  for (int it = 0; it < NITER; ++it) {
    gather();
#pragma unroll
    for (int p = 0; p < 2; ++p) {
      float xa;
      xa = xc[p]  - ta * (qc[p] + gc[p]);  xbc[p]  = 2.f * xa - xc[p];  xc[p]  = xa;
      xa = xd[p]  - ta * (qd[p] + gd[p]);  xbd[p]  = 2.f * xa - xd[p];  xd[p]  = xa;
      xa = xyc[p] - ta * gyc[p];           xbyc[p] = 2.f * xa - xyc[p]; xyc[p] = xa;
      xa = xyd[p] - ta * gyd[p];           xbyd[p] = 2.f * xa - xyd[p]; xyd[p] = xa;
      xa = xs[p]  - ta * gs[p];            xbs[p]  = 2.f * xa - xs[p];  xs[p]  = xa;
    }
    phaseB(false);
  }

  // output: c then d, each (256,96)
  if (lane < 48) {
    out[bi * 96 + 2 * lane]             = xc[0];
    out[bi * 96 + 2 * lane + 1]         = xc[1];
    out[24576 + bi * 96 + 2 * lane]     = xd[0];
    out[24576 + bi * 96 + 2 * lane + 1] = xd[1];
  }
}

extern "C" void kernel_launch(void* const* d_in, const int* in_sizes, int n_in,
                              void* d_out, int out_size, void* d_ws, size_t ws_size,
                              hipStream_t stream) {
  const float* price = (const float*)d_in[0];
  float* outp = (float*)d_out;
  hipLaunchKernelGGL(lp_solve_kernel, dim3(256), dim3(64), 0, stream, price, outp);
}

// Round 5
// 254.529 us; speedup vs baseline: 1.3892x; 1.3892x over previous
//
#include <hip/hip_runtime.h>
#include <math.h>

// DiffDispatchLP: batched (256x) PDHG, 400 iters.
// R5: R4's register-resident one-wave-per-item structure, with every
// __shfl_up/down (ds_bpermute, LDS pipe, ~50cy exposed latency each with a
// single resident wave -- R4's measured 1841 cy/iter) replaced by DPP
// wave_shr:1 / wave_shl:1 (VALU pipe, 1 inst, ~5cy). ~31 bpermutes -> ~33
// DPP ops. Same values bit-for-bit; only the lane-transport changes.
//
// Lane layout: lane l holds t=2l (chunk p=0) and t=2l+1 (p=1), l<48.
// All K/K^T couplings are t-offsets +-1..3 => same-lane or 1-2 lane shifts.
// Row-existence masks folded into per-row sigma multipliers; lanes >=48 and
// nonexistent rows carry exact zeros so shift edges read natural zeros.
//
// LP recap (T=96): vars c,d,yc,yd,s per t. Rows:
//  box(13/t), ramp(4/t,t>=1), switch(2/t,t<=94), min-dur(v,k=1..3,t<=95-k),
//  total-charge (0.25*sum(c)<=1200), eq(t=0..95) + eq96 (s[95]=0).

#define NITER 400
#define PITER 10

// ---- DPP lane shifts (gfx9 wave modes; row_shr/row_bcast family verified
// on this HW in R1's wave_sum64). bound_ctrl=1 zero-fills invalid lanes. ----
__device__ __forceinline__ float dpp_shr1(float x) {  // dst[i] = src[i-1], lane0 -> 0
  return __int_as_float(__builtin_amdgcn_update_dpp(
      0, __float_as_int(x), 0x138, 0xf, 0xf, true));   // wave_shr:1
}
__device__ __forceinline__ float dpp_shl1(float x) {  // dst[i] = src[i+1], lane63 -> 0
  return __int_as_float(__builtin_amdgcn_update_dpp(
      0, __float_as_int(x), 0x130, 0xf, 0xf, true));   // wave_shl:1
}

// Full wave64 sum via DPP (VALU pipe) -- verified in R1.
__device__ __forceinline__ float wave_sum64(float v) {
  float r = v;
  int x;
  x = __builtin_amdgcn_update_dpp(0, __float_as_int(r), 0x111, 0xf, 0xf, true);
  r += __int_as_float(x);
  x = __builtin_amdgcn_update_dpp(0, __float_as_int(r), 0x112, 0xf, 0xf, true);
  r += __int_as_float(x);
  x = __builtin_amdgcn_update_dpp(0, __float_as_int(r), 0x114, 0xf, 0xf, true);
  r += __int_as_float(x);
  x = __builtin_amdgcn_update_dpp(0, __float_as_int(r), 0x118, 0xf, 0xf, true);
  r += __int_as_float(x);
  x = __builtin_amdgcn_update_dpp(0, __float_as_int(r), 0x142, 0xa, 0xf, true);
  r += __int_as_float(x);
  x = __builtin_amdgcn_update_dpp(0, __float_as_int(r), 0x143, 0xc, 0xf, true);
  r += __int_as_float(x);
  return __int_as_float(__builtin_amdgcn_readlane(__float_as_int(r), 63));
}

__global__ __launch_bounds__(64, 1)
void lp_solve_kernel(const float* __restrict__ price, float* __restrict__ out) {
  const int lane = threadIdx.x;
  const int bi = blockIdx.x;
  const double ETA_D = sqrt(0.91);
  const float cET = (float)(-(ETA_D * 0.25));  // -ETA*DT (eq coeff on c)
  const float cDE = (float)(0.25 / ETA_D);     // DT/ETA (eq coeff on d)

  const float act = (lane < 48) ? 1.f : 0.f;
  // 0/1 row-existence masks (power mode); PDHG uses sigma*mask versions.
  const float m_r[2]  = { (lane >= 1 && lane < 48) ? 1.f : 0.f, act };  // ramp t>=1
  const float m_sw[2] = { act, (lane <= 46) ? 1.f : 0.f };              // sw t<=94
  const float m_md[3][2] = {
    { act,                        (lane <= 46) ? 1.f : 0.f },           // k=1: t<=94
    { (lane <= 46) ? 1.f : 0.f,   (lane <= 46) ? 1.f : 0.f },           // k=2: t<=93
    { (lane <= 46) ? 1.f : 0.f,   (lane <= 45) ? 1.f : 0.f }            // k=3: t<=92
  };

  // ---------------- state (all registers) ----------------
  float xc[2] = {0, 0}, xd[2] = {0, 0}, xyc[2] = {0, 0}, xyd[2] = {0, 0}, xs[2] = {0, 0};
  float xbc[2] = {0, 0}, xbd[2] = {0, 0}, xbyc[2] = {0, 0}, xbyd[2] = {0, 0}, xbs[2] = {0, 0};
  float qc[2] = {0, 0}, qd[2] = {0, 0};
  float yb[2][13];
#pragma unroll
  for (int p = 0; p < 2; ++p)
#pragma unroll
    for (int i = 0; i < 13; ++i) yb[p][i] = 0.f;
  float ymc[2][3] = {{0, 0, 0}, {0, 0, 0}}, ymd[2][3] = {{0, 0, 0}, {0, 0, 0}};
  float yr[2][4] = {{0, 0, 0, 0}, {0, 0, 0, 0}};
  float sw0[2] = {0, 0}, sw1[2] = {0, 0};
  float yeq[2] = {0, 0};
  float yeq96 = 0.f, ytc = 0.f;
  float uc[2] = {0, 0}, ud[2] = {0, 0}, msc[2] = {0, 0}, msd[2] = {0, 0};

  float sigv = 0.f, tauv = 0.f;
  float sa = 0.f, sr[2] = {0, 0}, ssw[2] = {0, 0};
  float smd[3][2] = {{0, 0}, {0, 0}, {0, 0}};

  // ---------------- phase B: row dots / dual updates ----------------
  auto phaseB = [&](bool power) {
    // xbar neighbor shifts (DPP). prev(t-1): p=0 needs lane-1's odd; p=1 same-lane even.
    float pxc[2], pxd[2], pxs[2], pxyc[2], pxyd[2];
    pxc[0]  = dpp_shr1(xbc[1]);  pxc[1]  = xbc[0];
    pxd[0]  = dpp_shr1(xbd[1]);  pxd[1]  = xbd[0];
    pxs[0]  = dpp_shr1(xbs[1]);  pxs[1]  = xbs[0];
    pxyc[0] = dpp_shr1(xbyc[1]); pxyc[1] = xbyc[0];
    pxyd[0] = dpp_shr1(xbyd[1]); pxyd[1] = xbyd[0];
    // next(t+k): chain shl1 (lanes >=48 are exact zeros, edge fills are 0).
    float nyc1[2], nyc2[2], nyc3[2], nyd1[2], nyd2[2], nyd3[2];
    nyc1[1] = dpp_shl1(xbyc[0]); nyc1[0] = xbyc[1];
    nyc2[1] = dpp_shl1(xbyc[1]); nyc2[0] = nyc1[1];
    nyc3[1] = dpp_shl1(nyc1[1]); nyc3[0] = nyc2[1];
    nyd1[1] = dpp_shl1(xbyd[0]); nyd1[0] = xbyd[1];
    nyd2[1] = dpp_shl1(xbyd[1]); nyd2[0] = nyd1[1];
    nyd3[1] = dpp_shl1(nyd1[1]); nyd3[0] = nyd2[1];

#pragma unroll
    for (int p = 0; p < 2; ++p) {
      const float c_ = xbc[p], d_ = xbd[p], yc_ = xbyc[p], yd_ = xbyd[p], s_ = xbs[p];
      // BOX (13 rows; in power mode xbar is act-masked so raw dots are 0 on l>=48)
      if (power) {
        yb[p][0] = c_;   yb[p][1] = d_;
        yb[p][2] = -c_;  yb[p][3] = -d_;
        yb[p][4] = -yc_; yb[p][5] = yc_;
        yb[p][6] = -yd_; yb[p][7] = yd_;
        yb[p][8] = -s_;  yb[p][9] = s_;
        yb[p][10] = yc_ + yd_;
        yb[p][11] = c_ - 195.f * yc_;
        yb[p][12] = d_ - 195.f * yd_;
      } else {
        yb[p][0]  = fmaxf(yb[p][0]  + sa * (c_ - 195.f), 0.f);
        yb[p][1]  = fmaxf(yb[p][1]  + sa * (d_ - 195.f), 0.f);
        yb[p][2]  = fmaxf(yb[p][2]  - sa * c_,           0.f);
        yb[p][3]  = fmaxf(yb[p][3]  - sa * d_,           0.f);
        yb[p][4]  = fmaxf(yb[p][4]  - sa * yc_,          0.f);
        yb[p][5]  = fmaxf(yb[p][5]  + sa * (yc_ - 1.f),  0.f);
        yb[p][6]  = fmaxf(yb[p][6]  - sa * yd_,          0.f);
        yb[p][7]  = fmaxf(yb[p][7]  + sa * (yd_ - 1.f),  0.f);
        yb[p][8]  = fmaxf(yb[p][8]  - sa * s_,           0.f);
        yb[p][9]  = fmaxf(yb[p][9]  + sa * (s_ - 800.f), 0.f);
        yb[p][10] = fmaxf(yb[p][10] + sa * (yc_ + yd_ - 1.f), 0.f);
        yb[p][11] = fmaxf(yb[p][11] + sa * (c_ - 195.f * yc_), 0.f);
        yb[p][12] = fmaxf(yb[p][12] + sa * (d_ - 195.f * yd_), 0.f);
      }
      // MIN-DURATION: dot(k,t) = v[t] - v[t-1] - v[t+k]
      {
        float dc1 = yc_ - pxyc[p] - nyc1[p];
        float dc2 = yc_ - pxyc[p] - nyc2[p];
        float dc3 = yc_ - pxyc[p] - nyc3[p];
        float dd1 = yd_ - pxyd[p] - nyd1[p];
        float dd2 = yd_ - pxyd[p] - nyd2[p];
        float dd3 = yd_ - pxyd[p] - nyd3[p];
        if (power) {
          ymc[p][0] = m_md[0][p] * dc1; ymc[p][1] = m_md[1][p] * dc2; ymc[p][2] = m_md[2][p] * dc3;
          ymd[p][0] = m_md[0][p] * dd1; ymd[p][1] = m_md[1][p] * dd2; ymd[p][2] = m_md[2][p] * dd3;
        } else {
          ymc[p][0] = fmaxf(ymc[p][0] + smd[0][p] * dc1, 0.f);
          ymc[p][1] = fmaxf(ymc[p][1] + smd[1][p] * dc2, 0.f);
          ymc[p][2] = fmaxf(ymc[p][2] + smd[2][p] * dc3, 0.f);
          ymd[p][0] = fmaxf(ymd[p][0] + smd[0][p] * dd1, 0.f);
          ymd[p][1] = fmaxf(ymd[p][1] + smd[1][p] * dd2, 0.f);
          ymd[p][2] = fmaxf(ymd[p][2] + smd[2][p] * dd3, 0.f);
        }
      }
      // RAMP
      {
        float dc = c_ - pxc[p], dd = d_ - pxd[p];
        if (power) {
          yr[p][0] = m_r[p] * dc; yr[p][1] = -m_r[p] * dc;
          yr[p][2] = m_r[p] * dd; yr[p][3] = -m_r[p] * dd;
        } else {
          yr[p][0] = fmaxf(yr[p][0] + sr[p] * (dc - 65.f),  0.f);
          yr[p][1] = fmaxf(yr[p][1] + sr[p] * (-dc - 65.f), 0.f);
          yr[p][2] = fmaxf(yr[p][2] + sr[p] * (dd - 65.f),  0.f);
          yr[p][3] = fmaxf(yr[p][3] + sr[p] * (-dd - 65.f), 0.f);
        }
      }
      // SWITCH
      {
        float d0 = yc_ + nyd1[p], d1 = yd_ + nyc1[p];
        if (power) { sw0[p] = m_sw[p] * d0; sw1[p] = m_sw[p] * d1; }
        else {
          sw0[p] = fmaxf(sw0[p] + ssw[p] * (d0 - 1.f), 0.f);
          sw1[p] = fmaxf(sw1[p] + ssw[p] * (d1 - 1.f), 0.f);
        }
      }
      // EQUALITY (free dual)
      {
        float de = s_ - pxs[p] + cET * c_ + cDE * d_;
        if (power) yeq[p] = act * de;
        else yeq[p] += sa * de;
      }
      // combos consumed by next gather (masked-zero rows keep these exact)
      uc[p] = yr[p][0] - yr[p][1];
      ud[p] = yr[p][2] - yr[p][3];
      msc[p] = ymc[p][0] + ymc[p][1] + ymc[p][2];
      msd[p] = ymd[p][0] + ymd[p][1] + ymd[p][2];
    }
    // eq96 (s[95]=0) and total-charge, both wave-uniform
    {
      float s95 = __int_as_float(__builtin_amdgcn_readlane(__float_as_int(xbs[1]), 47));
      if (power) yeq96 = s95; else yeq96 += sigv * s95;
      float tot = wave_sum64(xbc[0] + xbc[1]);
      if (power) ytc = 0.25f * tot;
      else ytc = fmaxf(ytc + sigv * (0.25f * tot - 1200.f), 0.f);
    }
  };

  // ---------------- phase A: K^T y gather, all 10 column-chunks ----------------
  float gc[2], gd[2], gyc[2], gyd[2], gs[2];
  auto gather = [&]() {
    float ucn[2], udn[2], mscn[2], msdn[2], eqn[2];
    ucn[0] = uc[1];   ucn[1] = dpp_shl1(uc[0]);
    udn[0] = ud[1];   udn[1] = dpp_shl1(ud[0]);
    mscn[0] = msc[1]; mscn[1] = dpp_shl1(msc[0]);
    msdn[0] = msd[1]; msdn[1] = dpp_shl1(msd[0]);
    eqn[0] = yeq[1];
    { float tdn = dpp_shl1(yeq[0]); eqn[1] = (lane == 47) ? -yeq96 : tdn; }
    float sw1p[2], sw0p[2];
    sw1p[0] = dpp_shr1(sw1[1]); sw1p[1] = sw1[0];
    sw0p[0] = dpp_shr1(sw0[1]); sw0p[1] = sw0[0];
    float pc1[2], pc2[2], pc3[2], pd1[2], pd2[2], pd3[2];
    pc1[0] = dpp_shr1(ymc[1][0]); pc1[1] = ymc[0][0];
    pc2[0] = dpp_shr1(ymc[0][1]); pc2[1] = dpp_shr1(ymc[1][1]);
    pc3[1] = dpp_shr1(ymc[0][2]); pc3[0] = dpp_shr1(dpp_shr1(ymc[1][2]));
    pd1[0] = dpp_shr1(ymd[1][0]); pd1[1] = ymd[0][0];
    pd2[0] = dpp_shr1(ymd[0][1]); pd2[1] = dpp_shr1(ymd[1][1]);
    pd3[1] = dpp_shr1(ymd[0][2]); pd3[0] = dpp_shr1(dpp_shr1(ymd[1][2]));
#pragma unroll
    for (int p = 0; p < 2; ++p) {
      gc[p] = (yb[p][0] - yb[p][2] + yb[p][11]) + uc[p] - ucn[p]
            + 0.25f * ytc + cET * yeq[p];
      gd[p] = (yb[p][1] - yb[p][3] + yb[p][12]) + ud[p] - udn[p] + cDE * yeq[p];
      gyc[p] = (-yb[p][4] + yb[p][5] + yb[p][10] - 195.f * yb[p][11])
             + sw0[p] + sw1p[p] + msc[p] - mscn[p] - pc1[p] - pc2[p] - pc3[p];
      gyd[p] = (-yb[p][6] + yb[p][7] + yb[p][10] - 195.f * yb[p][12])
             + sw1[p] + sw0p[p] + msd[p] - msdn[p] - pd1[p] - pd2[p] - pd3[p];
      gs[p] = (-yb[p][8] + yb[p][9]) + yeq[p] - eqn[p];
    }
  };

  // ================= power iteration: ||K||_2 =================
#pragma unroll
  for (int p = 0; p < 2; ++p) {
    xbc[p] = act; xbd[p] = act; xbyc[p] = act; xbyd[p] = act; xbs[p] = act;
  }
  float lam2 = 1.f;
  for (int pit = 0; pit < PITER; ++pit) {
    phaseB(true);
    gather();
    float part = gc[0] * gc[0] + gc[1] * gc[1] + gd[0] * gd[0] + gd[1] * gd[1]
               + gyc[0] * gyc[0] + gyc[1] * gyc[1] + gyd[0] * gyd[0] + gyd[1] * gyd[1]
               + gs[0] * gs[0] + gs[1] * gs[1];
    part *= act;
    lam2 = sqrtf(wave_sum64(part));
    float inv = act / lam2;
#pragma unroll
    for (int p = 0; p < 2; ++p) {
      xbc[p] = gc[p] * inv; xbd[p] = gd[p] * inv;
      xbyc[p] = gyc[p] * inv; xbyd[p] = gyd[p] * inv; xbs[p] = gs[p] * inv;
    }
  }
  tauv = (float)(0.9 / sqrt((double)lam2));
  sigv = tauv;
  // sigma*mask row multipliers (loop-invariant)
  sa = sigv * act;
  sr[0] = sigv * m_r[0];  sr[1] = sigv * m_r[1];
  ssw[0] = sigv * m_sw[0]; ssw[1] = sigv * m_sw[1];
#pragma unroll
  for (int k = 0; k < 3; ++k) { smd[k][0] = sigv * m_md[k][0]; smd[k][1] = sigv * m_md[k][1]; }

  // reset all state for PDHG
#pragma unroll
  for (int p = 0; p < 2; ++p) {
#pragma unroll
    for (int i = 0; i < 13; ++i) yb[p][i] = 0.f;
#pragma unroll
    for (int k = 0; k < 3; ++k) { ymc[p][k] = 0.f; ymd[p][k] = 0.f; }
#pragma unroll
    for (int k = 0; k < 4; ++k) yr[p][k] = 0.f;
    sw0[p] = 0.f; sw1[p] = 0.f; yeq[p] = 0.f;
    uc[p] = 0.f; ud[p] = 0.f; msc[p] = 0.f; msd[p] = 0.f;
    xbc[p] = 0.f; xbd[p] = 0.f; xbyc[p] = 0.f; xbyd[p] = 0.f; xbs[p] = 0.f;
    xc[p] = 0.f; xd[p] = 0.f; xyc[p] = 0.f; xyd[p] = 0.f; xs[p] = 0.f;
  }
  yeq96 = 0.f; ytc = 0.f;

  // q loads (lanes >=48 nullified by tau*act)
  {
    const int l2 = (lane < 48) ? lane : 0;
    float p0 = price[bi * 96 + 2 * l2];
    float p1 = price[bi * 96 + 2 * l2 + 1];
    qc[0] = 0.25f * p0;  qc[1] = 0.25f * p1;
    qd[0] = -0.25f * p0; qd[1] = -0.25f * p1;
  }

  // ================= PDHG =================
  const float ta = tauv * act;
#pragma unroll 1
  for (int it = 0; it < NITER; ++it) {
    gather();
#pragma unroll
    for (int p = 0; p < 2; ++p) {
      float xa;
      xa = xc[p]  - ta * (qc[p] + gc[p]);  xbc[p]  = 2.f * xa - xc[p];  xc[p]  = xa;
      xa = xd[p]  - ta * (qd[p] + gd[p]);  xbd[p]  = 2.f * xa - xd[p];  xd[p]  = xa;
      xa = xyc[p] - ta * gyc[p];           xbyc[p] = 2.f * xa - xyc[p]; xyc[p] = xa;
      xa = xyd[p] - ta * gyd[p];           xbyd[p] = 2.f * xa - xyd[p]; xyd[p] = xa;
      xa = xs[p]  - ta * gs[p];            xbs[p]  = 2.f * xa - xs[p];  xs[p]  = xa;
    }
    phaseB(false);
  }

  // output: c then d, each (256,96)
  if (lane < 48) {
    out[bi * 96 + 2 * lane]             = xc[0];
    out[bi * 96 + 2 * lane + 1]         = xc[1];
    out[24576 + bi * 96 + 2 * lane]     = xd[0];
    out[24576 + bi * 96 + 2 * lane + 1] = xd[1];
  }
}

extern "C" void kernel_launch(void* const* d_in, const int* in_sizes, int n_in,
                              void* d_out, int out_size, void* d_ws, size_t ws_size,
                              hipStream_t stream) {
  const float* price = (const float*)d_in[0];
  float* outp = (float*)d_out;
  hipLaunchKernelGGL(lp_solve_kernel, dim3(256), dim3(64), 0, stream, price, outp);
}

// Round 6
// 225.627 us; speedup vs baseline: 1.5672x; 1.1281x over previous
//
#include <hip/hip_runtime.h>
#include <math.h>

// DiffDispatchLP: batched (256x) PDHG, 400 iters.
// R6: R5's zero-LDS one-wave-per-item structure, with the even/odd (p=0/1)
// chunk pair packed into ext_vector float2 so the elementwise bulk lowers to
// CDNA packed-FP32 VOP3P ops (v_pk_fma_f32 / v_pk_add_f32 / v_pk_max_f32,
// full-rate on gfx90a+). R5 measured issue-bound: 1 wave/CU, VALUBusy 22.3%
// of the 25% single-SIMD ceiling => ~560 inst x 2cy = 1254 cy/iter. Packing
// halves the ~450 elementwise insts; the ~36 DPP lane-shifts (32-bit only)
// and wave_sum64 stay scalar. Numerics bit-identical to R5 (same per-
// component expression trees).
//
// Lane layout: lane l holds t=2l (.x) and t=2l+1 (.y), l<48. All K/K^T
// couplings are t-offsets +-1..3 => same-lane or 1-2 lane DPP shifts.
// Row-existence masks folded into per-row sigma multipliers; lanes >=48 and
// nonexistent rows carry exact zeros so shift edges read natural zeros.

#define NITER 400
#define PITER 10

typedef float v2 __attribute__((ext_vector_type(2)));

// ---- DPP lane shifts (wave modes; verified family on this HW, R1/R5). ----
__device__ __forceinline__ float dpp_shr1(float x) {  // dst[i] = src[i-1], lane0 -> 0
  return __int_as_float(__builtin_amdgcn_update_dpp(
      0, __float_as_int(x), 0x138, 0xf, 0xf, true));   // wave_shr:1
}
__device__ __forceinline__ float dpp_shl1(float x) {  // dst[i] = src[i+1], lane63 -> 0
  return __int_as_float(__builtin_amdgcn_update_dpp(
      0, __float_as_int(x), 0x130, 0xf, 0xf, true));   // wave_shl:1
}

// Full wave64 sum via DPP (VALU pipe) -- verified in R1.
__device__ __forceinline__ float wave_sum64(float v) {
  float r = v;
  int x;
  x = __builtin_amdgcn_update_dpp(0, __float_as_int(r), 0x111, 0xf, 0xf, true);
  r += __int_as_float(x);
  x = __builtin_amdgcn_update_dpp(0, __float_as_int(r), 0x112, 0xf, 0xf, true);
  r += __int_as_float(x);
  x = __builtin_amdgcn_update_dpp(0, __float_as_int(r), 0x114, 0xf, 0xf, true);
  r += __int_as_float(x);
  x = __builtin_amdgcn_update_dpp(0, __float_as_int(r), 0x118, 0xf, 0xf, true);
  r += __int_as_float(x);
  x = __builtin_amdgcn_update_dpp(0, __float_as_int(r), 0x142, 0xa, 0xf, true);
  r += __int_as_float(x);
  x = __builtin_amdgcn_update_dpp(0, __float_as_int(r), 0x143, 0xc, 0xf, true);
  r += __int_as_float(x);
  return __int_as_float(__builtin_amdgcn_readlane(__float_as_int(r), 63));
}

__global__ __launch_bounds__(64, 1)
void lp_solve_kernel(const float* __restrict__ price, float* __restrict__ out) {
  const int lane = threadIdx.x;
  const int bi = blockIdx.x;
  const double ETA_D = sqrt(0.91);
  const float cET = (float)(-(ETA_D * 0.25));  // -ETA*DT (eq coeff on c)
  const float cDE = (float)(0.25 / ETA_D);     // DT/ETA (eq coeff on d)
  const v2 Z = {0.f, 0.f};

  const float act = (lane < 48) ? 1.f : 0.f;
  // row-existence masks packed over p (power mode); PDHG uses sigma*mask.
  const v2 m_r  = { (lane >= 1 && lane < 48) ? 1.f : 0.f, act };   // ramp t>=1
  const v2 m_sw = { act, (lane <= 46) ? 1.f : 0.f };               // sw t<=94
  const v2 m_md[3] = {
    { act,                      (lane <= 46) ? 1.f : 0.f },        // k=1: t<=94
    { (lane <= 46) ? 1.f : 0.f, (lane <= 46) ? 1.f : 0.f },        // k=2: t<=93
    { (lane <= 46) ? 1.f : 0.f, (lane <= 45) ? 1.f : 0.f }         // k=3: t<=92
  };

  // ---------------- state (all registers, p-packed) ----------------
  v2 xc = Z, xd = Z, xyc = Z, xyd = Z, xs = Z;
  v2 xbc = Z, xbd = Z, xbyc = Z, xbyd = Z, xbs = Z;
  v2 qc = Z, qd = Z;
  v2 yb[13];
#pragma unroll
  for (int i = 0; i < 13; ++i) yb[i] = Z;
  v2 ymc[3] = {Z, Z, Z}, ymd[3] = {Z, Z, Z};
  v2 yr[4] = {Z, Z, Z, Z};
  v2 sw0 = Z, sw1 = Z, yeq = Z;
  float yeq96 = 0.f, ytc = 0.f;
  v2 uc = Z, ud = Z, msc = Z, msd = Z;

  float sigv = 0.f, tauv = 0.f;
  float sa = 0.f;                 // sigma*act (per-lane scalar, broadcast)
  v2 sr = Z, ssw = Z, smd[3] = {Z, Z, Z};

  // ---------------- phase B: row dots / dual updates ----------------
  auto phaseB = [&](bool power) {
    // xbar neighbor shifts. prev(t-1): .x needs lane-1's odd; .y same-lane even.
    v2 pxc  = { dpp_shr1(xbc.y),  xbc.x };
    v2 pxd  = { dpp_shr1(xbd.y),  xbd.x };
    v2 pxs  = { dpp_shr1(xbs.y),  xbs.x };
    v2 pxyc = { dpp_shr1(xbyc.y), xbyc.x };
    v2 pxyd = { dpp_shr1(xbyd.y), xbyd.x };
    // next(t+k): chained shl1 (lanes >=48 are exact zeros -> edge fills 0).
    float a1 = dpp_shl1(xbyc.x), b1 = dpp_shl1(xbyc.y), c1 = dpp_shl1(a1);
    v2 nyc1 = { xbyc.y, a1 };
    v2 nyc2 = { a1, b1 };
    v2 nyc3 = { b1, c1 };
    float a2 = dpp_shl1(xbyd.x), b2 = dpp_shl1(xbyd.y), c2 = dpp_shl1(a2);
    v2 nyd1 = { xbyd.y, a2 };
    v2 nyd2 = { a2, b2 };
    v2 nyd3 = { b2, c2 };

    const v2 c_ = xbc, d_ = xbd, yc_ = xbyc, yd_ = xbyd, s_ = xbs;
    // BOX (13 rows; in power mode xbar is act-masked so raw dots are 0 on l>=48)
    if (power) {
      yb[0] = c_;   yb[1] = d_;
      yb[2] = -c_;  yb[3] = -d_;
      yb[4] = -yc_; yb[5] = yc_;
      yb[6] = -yd_; yb[7] = yd_;
      yb[8] = -s_;  yb[9] = s_;
      yb[10] = yc_ + yd_;
      yb[11] = c_ - 195.f * yc_;
      yb[12] = d_ - 195.f * yd_;
    } else {
      yb[0]  = __builtin_elementwise_max(yb[0]  + sa * (c_ - 195.f), Z);
      yb[1]  = __builtin_elementwise_max(yb[1]  + sa * (d_ - 195.f), Z);
      yb[2]  = __builtin_elementwise_max(yb[2]  - sa * c_,           Z);
      yb[3]  = __builtin_elementwise_max(yb[3]  - sa * d_,           Z);
      yb[4]  = __builtin_elementwise_max(yb[4]  - sa * yc_,          Z);
      yb[5]  = __builtin_elementwise_max(yb[5]  + sa * (yc_ - 1.f),  Z);
      yb[6]  = __builtin_elementwise_max(yb[6]  - sa * yd_,          Z);
      yb[7]  = __builtin_elementwise_max(yb[7]  + sa * (yd_ - 1.f),  Z);
      yb[8]  = __builtin_elementwise_max(yb[8]  - sa * s_,           Z);
      yb[9]  = __builtin_elementwise_max(yb[9]  + sa * (s_ - 800.f), Z);
      yb[10] = __builtin_elementwise_max(yb[10] + sa * (yc_ + yd_ - 1.f), Z);
      yb[11] = __builtin_elementwise_max(yb[11] + sa * (c_ - 195.f * yc_), Z);
      yb[12] = __builtin_elementwise_max(yb[12] + sa * (d_ - 195.f * yd_), Z);
    }
    // MIN-DURATION: dot(k,t) = v[t] - v[t-1] - v[t+k]
    {
      v2 base_c = yc_ - pxyc, base_d = yd_ - pxyd;
      v2 dc1 = base_c - nyc1, dc2 = base_c - nyc2, dc3 = base_c - nyc3;
      v2 dd1 = base_d - nyd1, dd2 = base_d - nyd2, dd3 = base_d - nyd3;
      if (power) {
        ymc[0] = m_md[0] * dc1; ymc[1] = m_md[1] * dc2; ymc[2] = m_md[2] * dc3;
        ymd[0] = m_md[0] * dd1; ymd[1] = m_md[1] * dd2; ymd[2] = m_md[2] * dd3;
      } else {
        ymc[0] = __builtin_elementwise_max(ymc[0] + smd[0] * dc1, Z);
        ymc[1] = __builtin_elementwise_max(ymc[1] + smd[1] * dc2, Z);
        ymc[2] = __builtin_elementwise_max(ymc[2] + smd[2] * dc3, Z);
        ymd[0] = __builtin_elementwise_max(ymd[0] + smd[0] * dd1, Z);
        ymd[1] = __builtin_elementwise_max(ymd[1] + smd[1] * dd2, Z);
        ymd[2] = __builtin_elementwise_max(ymd[2] + smd[2] * dd3, Z);
      }
    }
    // RAMP
    {
      v2 dc = c_ - pxc, dd = d_ - pxd;
      if (power) {
        yr[0] = m_r * dc; yr[1] = -m_r * dc;
        yr[2] = m_r * dd; yr[3] = -m_r * dd;
      } else {
        yr[0] = __builtin_elementwise_max(yr[0] + sr * (dc - 65.f),  Z);
        yr[1] = __builtin_elementwise_max(yr[1] + sr * (-dc - 65.f), Z);
        yr[2] = __builtin_elementwise_max(yr[2] + sr * (dd - 65.f),  Z);
        yr[3] = __builtin_elementwise_max(yr[3] + sr * (-dd - 65.f), Z);
      }
    }
    // SWITCH
    {
      v2 d0 = yc_ + nyd1, d1 = yd_ + nyc1;
      if (power) { sw0 = m_sw * d0; sw1 = m_sw * d1; }
      else {
        sw0 = __builtin_elementwise_max(sw0 + ssw * (d0 - 1.f), Z);
        sw1 = __builtin_elementwise_max(sw1 + ssw * (d1 - 1.f), Z);
      }
    }
    // EQUALITY (free dual)
    {
      v2 de = s_ - pxs + cET * c_ + cDE * d_;
      if (power) yeq = act * de;
      else yeq += sa * de;
    }
    // combos consumed by next gather (masked-zero rows keep these exact)
    uc = yr[0] - yr[1];
    ud = yr[2] - yr[3];
    msc = ymc[0] + ymc[1] + ymc[2];
    msd = ymd[0] + ymd[1] + ymd[2];
    // eq96 (s[95]=0) and total-charge, both wave-uniform
    {
      float s95 = __int_as_float(__builtin_amdgcn_readlane(__float_as_int(xbs.y), 47));
      if (power) yeq96 = s95; else yeq96 += sigv * s95;
      float tot = wave_sum64(xbc.x + xbc.y);
      if (power) ytc = 0.25f * tot;
      else ytc = fmaxf(ytc + sigv * (0.25f * tot - 1200.f), 0.f);
    }
  };

  // ---------------- phase A: K^T y gather, all 10 column-chunks ----------------
  v2 gc, gd, gyc, gyd, gs;
  auto gather = [&]() {
    v2 ucn  = { uc.y,  dpp_shl1(uc.x) };
    v2 udn  = { ud.y,  dpp_shl1(ud.x) };
    v2 mscn = { msc.y, dpp_shl1(msc.x) };
    v2 msdn = { msd.y, dpp_shl1(msd.x) };
    float tdn = dpp_shl1(yeq.x);
    v2 eqn = { yeq.y, (lane == 47) ? -yeq96 : tdn };
    v2 sw1p = { dpp_shr1(sw1.y), sw1.x };
    v2 sw0p = { dpp_shr1(sw0.y), sw0.x };
    v2 pc1 = { dpp_shr1(ymc[0].y), ymc[0].x };
    v2 pc2 = { dpp_shr1(ymc[1].x), dpp_shr1(ymc[1].y) };
    v2 pc3 = { dpp_shr1(dpp_shr1(ymc[2].y)), dpp_shr1(ymc[2].x) };
    v2 pd1 = { dpp_shr1(ymd[0].y), ymd[0].x };
    v2 pd2 = { dpp_shr1(ymd[1].x), dpp_shr1(ymd[1].y) };
    v2 pd3 = { dpp_shr1(dpp_shr1(ymd[2].y)), dpp_shr1(ymd[2].x) };
    gc = (yb[0] - yb[2] + yb[11]) + uc - ucn + 0.25f * ytc + cET * yeq;
    gd = (yb[1] - yb[3] + yb[12]) + ud - udn + cDE * yeq;
    gyc = (-yb[4] + yb[5] + yb[10] - 195.f * yb[11])
        + sw0 + sw1p + msc - mscn - pc1 - pc2 - pc3;
    gyd = (-yb[6] + yb[7] + yb[10] - 195.f * yb[12])
        + sw1 + sw0p + msd - msdn - pd1 - pd2 - pd3;
    gs = (-yb[8] + yb[9]) + yeq - eqn;
  };

  // ================= power iteration: ||K||_2 =================
  xbc = act; xbd = act; xbyc = act; xbyd = act; xbs = act;
  float lam2 = 1.f;
  for (int pit = 0; pit < PITER; ++pit) {
    phaseB(true);
    gather();
    v2 pv = gc * gc + gd * gd + gyc * gyc + gyd * gyd + gs * gs;
    float part = (pv.x + pv.y) * act;
    lam2 = sqrtf(wave_sum64(part));
    float inv = act / lam2;
    xbc = gc * inv; xbd = gd * inv;
    xbyc = gyc * inv; xbyd = gyd * inv; xbs = gs * inv;
  }
  tauv = (float)(0.9 / sqrt((double)lam2));
  sigv = tauv;
  // sigma*mask row multipliers (loop-invariant)
  sa = sigv * act;
  sr = sigv * m_r;
  ssw = sigv * m_sw;
#pragma unroll
  for (int k = 0; k < 3; ++k) smd[k] = sigv * m_md[k];

  // reset all state for PDHG
#pragma unroll
  for (int i = 0; i < 13; ++i) yb[i] = Z;
#pragma unroll
  for (int k = 0; k < 3; ++k) { ymc[k] = Z; ymd[k] = Z; }
#pragma unroll
  for (int k = 0; k < 4; ++k) yr[k] = Z;
  sw0 = Z; sw1 = Z; yeq = Z;
  uc = Z; ud = Z; msc = Z; msd = Z;
  xbc = Z; xbd = Z; xbyc = Z; xbyd = Z; xbs = Z;
  xc = Z; xd = Z; xyc = Z; xyd = Z; xs = Z;
  yeq96 = 0.f; ytc = 0.f;

  // q loads (lanes >=48 nullified by tau*act)
  {
    const int l2 = (lane < 48) ? lane : 0;
    float p0 = price[bi * 96 + 2 * l2];
    float p1 = price[bi * 96 + 2 * l2 + 1];
    qc = (v2){ 0.25f * p0, 0.25f * p1 };
    qd = (v2){ -0.25f * p0, -0.25f * p1 };
  }

  // ================= PDHG =================
  const float ta = tauv * act;
#pragma unroll 1
  for (int it = 0; it < NITER; ++it) {
    gather();
    {
      v2 xa;
      xa = xc  - ta * (qc + gc);  xbc  = 2.f * xa - xc;  xc  = xa;
      xa = xd  - ta * (qd + gd);  xbd  = 2.f * xa - xd;  xd  = xa;
      xa = xyc - ta * gyc;        xbyc = 2.f * xa - xyc; xyc = xa;
      xa = xyd - ta * gyd;        xbyd = 2.f * xa - xyd; xyd = xa;
      xa = xs  - ta * gs;         xbs  = 2.f * xa - xs;  xs  = xa;
    }
    phaseB(false);
  }

  // output: c then d, each (256,96)
  if (lane < 48) {
    out[bi * 96 + 2 * lane]             = xc.x;
    out[bi * 96 + 2 * lane + 1]         = xc.y;
    out[24576 + bi * 96 + 2 * lane]     = xd.x;
    out[24576 + bi * 96 + 2 * lane + 1] = xd.y;
  }
}

extern "C" void kernel_launch(void* const* d_in, const int* in_sizes, int n_in,
                              void* d_out, int out_size, void* d_ws, size_t ws_size,
                              hipStream_t stream) {
  const float* price = (const float*)d_in[0];
  float* outp = (float*)d_out;
  hipLaunchKernelGGL(lp_solve_kernel, dim3(256), dim3(64), 0, stream, price, outp);
}